// Round 13
// baseline (172.070 us; speedup 1.0000x reference)
//
#include <hip/hip_runtime.h>
#include <stdint.h>

// Problem constants (fixed by reference setup_inputs)
constexpr int B_ = 8, N_ = 2048, M_ = 2048, K_ = 64;

// Workspace layout (float offsets). Ends at 184320 floats (737 KB).
constexpr int WS_QB   = 1024;    // [B*N]          qb = 0.5 b^T S b
constexpr int WS_U9   = 18432;   // [B*10*2048]    SoA full planes: u0..u8, qa
constexpr int WS_PART = 182272;  // [2048]         per-block partial colsums
constexpr int UPL = 2048;            // floats per full plane
constexpr int UCH = 10 * UPL;        // 20480 floats = 80 KB per batch

// ---------------------------------------------------------------------------
// Kernel 1 (fused per-batch prep): grid = B, 256 threads. r10-verified.
//   phase 1: raw moments; phase 2: wave-0 fp64 GJ pinv -> S; phase 3: qb;
//   phase 4: U9/qa in SoA FULL-PLANE layout (stride 2048; topk reads direct).
// ---------------------------------------------------------------------------
__global__ __launch_bounds__(256) void stats_pinv_kernel(const float* __restrict__ outputs,
                                                         const float* __restrict__ targets,
                                                         float* __restrict__ ws)
{
    const int b = blockIdx.x, t = threadIdx.x;

    float s[9], cc[45];
#pragma unroll
    for (int d = 0; d < 9; ++d) s[d] = 0.f;
#pragma unroll
    for (int i = 0; i < 45; ++i) cc[i] = 0.f;

    const float* T = targets + (size_t)b * M_ * 9;
#pragma unroll
    for (int r = 0; r < 8; ++r) {
        const float* row = T + (r * 256 + t) * 9;
        float y[9];
#pragma unroll
        for (int d = 0; d < 9; ++d) { y[d] = row[d]; s[d] += y[d]; }
        int idx = 0;
#pragma unroll
        for (int i = 0; i < 9; ++i)
#pragma unroll
            for (int j = i; j < 9; ++j) { cc[idx] = fmaf(y[i], y[j], cc[idx]); ++idx; }
    }
#pragma unroll
    for (int o = 32; o; o >>= 1) {
#pragma unroll
        for (int d = 0; d < 9; ++d) s[d] += __shfl_xor(s[d], o, 64);
#pragma unroll
        for (int i = 0; i < 45; ++i) cc[i] += __shfl_xor(cc[i], o, 64);
    }
    __shared__ float red[4][54];
    __shared__ float smom[54];
    const int wave = t >> 6, lane = t & 63;
    if (lane == 0) {
#pragma unroll
        for (int d = 0; d < 9; ++d) red[wave][d] = s[d];
#pragma unroll
        for (int i = 0; i < 45; ++i) red[wave][9 + i] = cc[i];
    }
    __syncthreads();

    // ---- wave-0-only pinv (no barriers inside; r10-verified, absmax 0.0) ----
    __shared__ double As[81], G[81], Inv[81], Cm[81], fcol[9], smu[9];
    __shared__ float sSf[81], sMuF[9];

    if (wave == 0) {
        if (t < 54) smom[t] = red[0][t] + red[1][t] + red[2][t] + red[3][t];
        if (t < 9) {
            const double m = (double)smom[t] / M_;
            smu[t] = m;
            sMuF[t] = (float)m;
        }
#pragma unroll
        for (int cc2 = 0; cc2 < 2; ++cc2) {
            const int c = lane + cc2 * 64;
            if (cc2 == 0 || lane < 17) {
                const int i = c / 9, j = c % 9;
                const int ii = i < j ? i : j, jj = i < j ? j : i;
                const int tri = ii * 9 - ii * (ii - 1) / 2 + (jj - ii);
                As[c] = (double)smom[9 + tri] - (double)M_ * smu[i] * smu[j];
            }
        }
#pragma unroll
        for (int cc2 = 0; cc2 < 2; ++cc2) {
            const int c = lane + cc2 * 64;
            if (cc2 == 0 || lane < 17) {
                const int i = c / 9, j = c % 9;
                double sv = 0.0;
#pragma unroll
                for (int k = 0; k < 9; ++k) sv += As[k * 9 + i] * As[k * 9 + j];
                G[c] = sv;
                Inv[c] = (i == j) ? 1.0 : 0.0;
            }
        }
#pragma unroll 1
        for (int col = 0; col < 9; ++col) {
            const double p = G[col * 9 + col];
            if (lane >= col * 9 && lane < col * 9 + 9) { G[lane] /= p; Inv[lane] /= p; }
            if (lane < 17) {
                const int c2 = lane + 64;
                if (c2 >= col * 9 && c2 < col * 9 + 9) { G[c2] /= p; Inv[c2] /= p; }
            }
            if (lane < 9 && lane != col) fcol[lane] = G[lane * 9 + col];
            {
                const int r = lane / 9, j = lane % 9;
                if (r != col) {
                    const double f = fcol[r];
                    G[lane]   -= f * G[col * 9 + j];
                    Inv[lane] -= f * Inv[col * 9 + j];
                }
            }
            if (lane < 17) {
                const int c2 = lane + 64;
                const int r = c2 / 9, j = c2 % 9;
                if (r != col) {
                    const double f = fcol[r];
                    G[c2]   -= f * G[col * 9 + j];
                    Inv[c2] -= f * Inv[col * 9 + j];
                }
            }
        }
#pragma unroll
        for (int cc2 = 0; cc2 < 2; ++cc2) {
            const int c = lane + cc2 * 64;
            if (cc2 == 0 || lane < 17) {
                const int i = c / 9, j = c % 9;
                double sv = 0.0;
#pragma unroll
                for (int k = 0; k < 9; ++k) sv += Inv[i * 9 + k] * As[j * 9 + k];
                Cm[c] = sv;
            }
        }
#pragma unroll
        for (int cc2 = 0; cc2 < 2; ++cc2) {
            const int c = lane + cc2 * 64;
            if (cc2 == 0 || lane < 17) {
                const int i = c / 9, j = c % 9;
                sSf[c] = (float)(Cm[i * 9 + j] + Cm[j * 9 + i]);
            }
        }
    }
    __syncthreads();  // publish sSf/sMuF to all waves

    // ---- qb phase ----
    for (int c = t; c < N_; c += 256) {
        const float* r = outputs + ((size_t)b * N_ + c) * 9;
        float bv[9];
#pragma unroll
        for (int d = 0; d < 9; ++d) bv[d] = r[d];
        float q = 0.f;
#pragma unroll
        for (int d = 0; d < 9; ++d) {
            float v = 0.f;
#pragma unroll
            for (int e = 0; e < 9; ++e) v = fmaf(sSf[d * 9 + e], bv[e], v);
            q = fmaf(v, bv[d], q);
        }
        ws[WS_QB + b * N_ + c] = 0.5f * q;
    }

    // ---- U9 phase: u = S a, qa = 0.5 a^T S a, full-plane SoA layout ----
    float* base = ws + WS_U9 + (size_t)b * UCH;
    for (int m = t; m < M_; m += 256) {
        const float* r = T + (size_t)m * 9;
        float a[9];
#pragma unroll
        for (int d = 0; d < 9; ++d) a[d] = r[d] - sMuF[d];
        float qa = 0.f;
#pragma unroll
        for (int d = 0; d < 9; ++d) {
            float u = 0.f;
#pragma unroll
            for (int e = 0; e < 9; ++e) u = fmaf(sSf[d * 9 + e], a[e], u);
            base[d * UPL + m] = u;
            qa = fmaf(u, a[d], qa);
        }
        base[9 * UPL + m] = 0.5f * qa;
    }
}

// ---------------------------------------------------------------------------
// Kernel 2: sum-of-top-64 per column -- DIRECT-FROM-L2, NO LDS TILE.
//
// Rationale (r12 counters + 6 rounds of structure tests): U9 (640 KB) is
// fully L2/L3-resident (FETCH_SIZE ~3 MB for 1.3 GB of logical reads), yet
// the r7 structure staged it through LDS with 6 block-wide barriers that
// phase-lock all 4 resident blocks -- neither pipe ever exceeded ~50%.
// Guide Common-mistake #7: don't stage what the cache already holds.
// Here every wave free-runs: 16 groups of 2 rows, 10 independent float2
// L2 loads per group (20 VGPR in flight -- fits the 64-VGPR budget with
// keys<=30 + ba 9; the r3/r11 spill trap avoided by the small group size).
// L2 floor: 16384 cols x 80 KB = 1.31 GB @ ~34.5 TB/s ~= 38 us.
// ZERO barriers until the tiny final block-reduce.
//
// Search/keys: EXACT r7 version (65.6us proven; r12's "shaves" regressed and
// are reverted): 32 register keys, sign-branch monotone transform,
// ballot+popcll counting, bits 30..8, block-private partials (no atomics).
// ---------------------------------------------------------------------------
__global__ __launch_bounds__(512) void topk_kernel(const float* __restrict__ outputs,
                                                   float* __restrict__ ws)
{
    __shared__ float wsum[8];
    const int b = blockIdx.y;
    const int tid = threadIdx.x;
    const int wave = tid >> 6, lane = tid & 63;
    const int n = blockIdx.x * 8 + wave;  // this wave's column

    const float* brow = outputs + ((size_t)b * N_ + n) * 9;
    float ba[9];
#pragma unroll
    for (int d = 0; d < 9; ++d) ba[d] = brow[d];

    const float* ub = ws + WS_U9 + (size_t)b * UCH;

    unsigned ua[32];
#pragma unroll
    for (int g = 0; g < 16; ++g) {
        const int r0 = g * 128 + lane * 2;  // 2 consecutive rows per lane
        const float2 qv = *(const float2*)(ub + 9 * UPL + r0);
        float a0 = qv.x, a1 = qv.y;
#pragma unroll
        for (int d = 0; d < 9; ++d) {
            const float2 uv = *(const float2*)(ub + d * UPL + r0);
            const float bd = ba[d];
            a0 = fmaf(-uv.x, bd, a0);
            a1 = fmaf(-uv.y, bd, a1);
        }
        const unsigned x0 = __float_as_uint(a0), x1 = __float_as_uint(a1);
        // monotone uint key (order-preserving float->uint), r7-exact
        ua[g * 2 + 0] = (x0 & 0x80000000u) ? ~x0 : (x0 | 0x80000000u);
        ua[g * 2 + 1] = (x1 & 0x80000000u) ? ~x1 : (x1 | 0x80000000u);
    }

    // Binary search for tau (64th largest), bits 30..8. Bit 31 pre-set (keys
    // of non-negative floats; >=64 of 2048 distances positive -- verified by
    // eleven passing rounds). 24-bit truncation: final-mean bias < 1e-7
    // (threshold 3.7e-4). cnt/threshold/decision are wave-uniform scalars.
    unsigned ca = 0x80000000u;
#pragma unroll 1
    for (int bit = 30; bit >= 8; --bit) {
        const unsigned ta = ca | (1u << bit);
        int cnt = 0;
#pragma unroll
        for (int j = 0; j < 32; ++j) cnt += __popcll(__ballot(ua[j] >= ta));
        if (cnt >= K_) ca = ta;
    }

    // Exact sum of strictly-greater values + tie adjustment at tau.
    float sa = 0.f;
    int ga = 0;
#pragma unroll
    for (int j = 0; j < 32; ++j) {
        const unsigned va = ua[j];
        const bool pa = va > ca;
        if (pa) sa += __uint_as_float(va ^ 0x80000000u);  // bit31 set: ca >= 0x80000000
        ga += __popcll(__ballot(pa));                     // wave-uniform
    }
#pragma unroll
    for (int o = 32; o; o >>= 1) sa += __shfl_xor(sa, o, 64);

    if (lane == 0) {
        const float tva = __uint_as_float(ca ^ 0x80000000u);
        const float qb = ws[WS_QB + b * N_ + n];
        wsum[wave] = sa + (float)(K_ - ga) * tva + (float)K_ * qb;
    }
    __syncthreads();
    if (tid == 0) {
        float tsum = 0.f;
#pragma unroll
        for (int w = 0; w < 8; ++w) tsum += wsum[w];
        ws[WS_PART + b * (N_ / 8) + blockIdx.x] = tsum;  // block-private, NO atomic
    }
}

// ---------------------------------------------------------------------------
// Kernel 3: sum the 2048 per-block partials, scale by exact 2^-20, write out.
// ---------------------------------------------------------------------------
__global__ __launch_bounds__(256) void finalize_kernel(const float* __restrict__ ws,
                                                       float* __restrict__ out)
{
    const int tid = threadIdx.x;
    float s = 0.f;
#pragma unroll
    for (int i = 0; i < 8; ++i) s += ws[WS_PART + i * 256 + tid];
#pragma unroll
    for (int o = 32; o; o >>= 1) s += __shfl_xor(s, o, 64);
    __shared__ float r4[4];
    if ((tid & 63) == 0) r4[tid >> 6] = s;
    __syncthreads();
    if (tid == 0) out[0] = (r4[0] + r4[1] + r4[2] + r4[3]) * (1.0f / 1048576.0f);
}

// ---------------------------------------------------------------------------
extern "C" void kernel_launch(void* const* d_in, const int* in_sizes, int n_in,
                              void* d_out, int out_size, void* d_ws, size_t ws_size,
                              hipStream_t stream)
{
    (void)in_sizes; (void)n_in; (void)out_size; (void)ws_size;
    const float* outputs = (const float*)d_in[0];  // (B,N,9) fp32
    const float* targets = (const float*)d_in[1];  // (B,M,9) fp32
    float* ws  = (float*)d_ws;
    float* out = (float*)d_out;

    stats_pinv_kernel<<<B_, 256, 0, stream>>>(outputs, targets, ws);
    topk_kernel<<<dim3(N_ / 8, B_), 512, 0, stream>>>(outputs, ws);
    finalize_kernel<<<1, 256, 0, stream>>>(ws, out);
}

// Round 14
// 132.876 us; speedup vs baseline: 1.2950x; 1.2950x over previous
//
#include <hip/hip_runtime.h>
#include <stdint.h>

// Problem constants (fixed by reference setup_inputs)
constexpr int B_ = 8, N_ = 2048, M_ = 2048, K_ = 64;

// Workspace layout (float offsets). Ends at 184320 floats (737 KB).
constexpr int WS_QB   = 1024;    // [B*N]           qb = 0.5 b^T S b
constexpr int WS_U9   = 18432;   // [B*2*10*1024]   SoA halves: planes u0..u8, qa
constexpr int WS_PART = 182272;  // [2048]          per-block partial colsums
constexpr int PL = 1024;             // floats per plane within a half
constexpr int CHUNK = 10 * PL;       // 10 planes = 40 KB per (b, half)

// ---------------------------------------------------------------------------
// Kernel 1 (fused per-batch prep): grid = B, 256 threads. EXACT r7 version
// (the 134.0us config). Barrier-GJ (r10's wave-0 variant measured neutral).
//   phase 1: raw moments Sum(y)[9], Sum(y y^T)[45] over 2048 rows (8/thread)
//   phase 2: cov -> S = C + C^T, C = pinv(cov) via fp64 Gauss-Jordan in LDS
//   phase 3: qb_n = 0.5 b^T S b (S broadcast from LDS)
//   phase 4: U9/qa rows in SoA HALF layout (coalesced per-plane stores)
// ---------------------------------------------------------------------------
__global__ __launch_bounds__(256) void stats_pinv_kernel(const float* __restrict__ outputs,
                                                         const float* __restrict__ targets,
                                                         float* __restrict__ ws)
{
    const int b = blockIdx.x, t = threadIdx.x;

    float s[9], cc[45];
#pragma unroll
    for (int d = 0; d < 9; ++d) s[d] = 0.f;
#pragma unroll
    for (int i = 0; i < 45; ++i) cc[i] = 0.f;

    const float* T = targets + (size_t)b * M_ * 9;
#pragma unroll
    for (int r = 0; r < 8; ++r) {
        const float* row = T + (r * 256 + t) * 9;
        float y[9];
#pragma unroll
        for (int d = 0; d < 9; ++d) { y[d] = row[d]; s[d] += y[d]; }
        int idx = 0;
#pragma unroll
        for (int i = 0; i < 9; ++i)
#pragma unroll
            for (int j = i; j < 9; ++j) { cc[idx] = fmaf(y[i], y[j], cc[idx]); ++idx; }
    }
#pragma unroll
    for (int o = 32; o; o >>= 1) {
#pragma unroll
        for (int d = 0; d < 9; ++d) s[d] += __shfl_xor(s[d], o, 64);
#pragma unroll
        for (int i = 0; i < 45; ++i) cc[i] += __shfl_xor(cc[i], o, 64);
    }
    __shared__ float red[4][54];
    __shared__ float smom[54];
    const int wave = t >> 6, lane = t & 63;
    if (lane == 0) {
#pragma unroll
        for (int d = 0; d < 9; ++d) red[wave][d] = s[d];
#pragma unroll
        for (int i = 0; i < 45; ++i) red[wave][9 + i] = cc[i];
    }
    __syncthreads();
    if (t < 54) smom[t] = red[0][t] + red[1][t] + red[2][t] + red[3][t];
    __syncthreads();

    // ---- pinv phase (fp64 Gauss-Jordan; t < 81 active) ----
    __shared__ double As[81], G[81], Inv[81], Cm[81], fcol[9], smu[9];
    __shared__ float sSf[81], sMuF[9];

    if (t < 9) {
        const double m = (double)smom[t] / M_;
        smu[t] = m;
        const float mf = (float)m;
        sMuF[t] = mf;
    }
    __syncthreads();
    if (t < 81) {  // cov = Sum(yy^T) - M mu mu^T
        const int i = t / 9, j = t % 9;
        const int ii = i < j ? i : j, jj = i < j ? j : i;
        const int tri = ii * 9 - ii * (ii - 1) / 2 + (jj - ii);
        As[t] = (double)smom[9 + tri] - (double)M_ * smu[i] * smu[j];
    }
    __syncthreads();
    if (t < 81) {
        const int i = t / 9, j = t % 9;
        double sv = 0.0;
#pragma unroll
        for (int k = 0; k < 9; ++k) sv += As[k * 9 + i] * As[k * 9 + j];  // A^T A
        G[t] = sv;
        Inv[t] = (i == j) ? 1.0 : 0.0;
    }
    __syncthreads();

    for (int col = 0; col < 9; ++col) {
        const double p = G[col * 9 + col];  // all read before any write
        __syncthreads();
        if (t < 9) {
            G[col * 9 + t] /= p;
            Inv[col * 9 + t] /= p;
        }
        __syncthreads();
        if (t < 9 && t != col) fcol[t] = G[t * 9 + col];
        __syncthreads();
        if (t < 81) {
            const int r = t / 9, j = t % 9;
            if (r != col) {
                const double f = fcol[r];
                G[t]   -= f * G[col * 9 + j];
                Inv[t] -= f * Inv[col * 9 + j];
            }
        }
        __syncthreads();
    }

    if (t < 81) {  // C = inv(A^T A) A^T
        const int i = t / 9, j = t % 9;
        double sv = 0.0;
#pragma unroll
        for (int k = 0; k < 9; ++k) sv += Inv[i * 9 + k] * As[j * 9 + k];
        Cm[t] = sv;
    }
    __syncthreads();
    if (t < 81) {
        const int i = t / 9, j = t % 9;
        sSf[t] = (float)(Cm[i * 9 + j] + Cm[j * 9 + i]);  // S = C + C^T
    }
    __syncthreads();

    // ---- qb phase: 8 columns per thread, S broadcast from LDS ----
    for (int c = t; c < N_; c += 256) {
        const float* r = outputs + ((size_t)b * N_ + c) * 9;
        float bv[9];
#pragma unroll
        for (int d = 0; d < 9; ++d) bv[d] = r[d];
        float q = 0.f;
#pragma unroll
        for (int d = 0; d < 9; ++d) {
            float v = 0.f;
#pragma unroll
            for (int e = 0; e < 9; ++e) v = fmaf(sSf[d * 9 + e], bv[e], v);
            q = fmaf(v, bv[d], q);
        }
        ws[WS_QB + b * N_ + c] = 0.5f * q;
    }

    // ---- U9 phase: u = S a, qa = 0.5 a^T S a, SoA HALF layout ----
    for (int m = t; m < M_; m += 256) {
        const int h = m >> 10, mm = m & 1023;
        const float* r = T + (size_t)m * 9;
        float a[9];
#pragma unroll
        for (int d = 0; d < 9; ++d) a[d] = r[d] - sMuF[d];
        float* base = ws + WS_U9 + (size_t)(b * 2 + h) * CHUNK;
        float qa = 0.f;
#pragma unroll
        for (int d = 0; d < 9; ++d) {
            float u = 0.f;
#pragma unroll
            for (int e = 0; e < 9; ++e) u = fmaf(sSf[d * 9 + e], a[e], u);
            base[d * PL + mm] = u;
            qa = fmaf(u, a[d], qa);
        }
        base[9 * PL + mm] = 0.5f * qa;
    }
}

// ---------------------------------------------------------------------------
// Kernel 2: sum-of-top-64 per column -- r7 structure, the proven best across
// 9 tested topk variants (65.6us; everything else 70-241us or hung).
// 512 threads = 8 waves, one column/wave; M in 2 halves of 1024 rows staged
// into one 40 KB LDS SoA chunk (40960 B exactly -> 4 blocks/CU, 32 waves/CU).
//
// Sole r14 change vs r7: 1-op key transform (key = x ^ 0x80000000), isolated
// from r12's confounded bundle. Bit-identical to r7 for non-negative
// distances (x|0x8.. == x^0x8.. when bit31=0); negative distances map below
// 0x80000000 <= ca so they never enter any count/sum/tie path -- same
// invariant (top-64 positive) r7 already relies on, verified 11 rounds.
// Strictly fewer VALU ops, no VGPR delta, no numerics delta.
// ---------------------------------------------------------------------------
__global__ __launch_bounds__(512) void topk_kernel(const float* __restrict__ outputs,
                                                   float* __restrict__ ws)
{
    __shared__ float sT[10 * PL];  // exactly 40960 B; no other LDS objects
    const int b = blockIdx.y;
    const int tid = threadIdx.x;
    const int wave = tid >> 6, lane = tid & 63;
    const int n = blockIdx.x * 8 + wave;  // this wave's column

    const float* brow = outputs + ((size_t)b * N_ + n) * 9;
    float ba[9];
#pragma unroll
    for (int d = 0; d < 9; ++d) ba[d] = brow[d];

    unsigned ua[32];
#pragma unroll
    for (int h = 0; h < 2; ++h) {
        __syncthreads();  // protect LDS from previous phase's readers
        const float4* src = (const float4*)(ws + WS_U9 + (size_t)(b * 2 + h) * CHUNK);
        float4* dst = (float4*)sT;
        // 2560 float4s over 512 threads: 5 unrolled coalesced copies
#pragma unroll
        for (int i = 0; i < 5; ++i) dst[i * 512 + tid] = src[i * 512 + tid];
        __syncthreads();

#pragma unroll
        for (int g = 0; g < 4; ++g) {
            const int r0 = g * 256 + lane * 4;  // 4 consecutive rows per lane
            const float4 qv = *(const float4*)(sT + 9 * PL + r0);
            float a0 = qv.x, a1 = qv.y, a2 = qv.z, a3 = qv.w;
#pragma unroll
            for (int d = 0; d < 9; ++d) {
                const float4 uv = *(const float4*)(sT + d * PL + r0);
                const float bd = ba[d];
                a0 = fmaf(-uv.x, bd, a0);
                a1 = fmaf(-uv.y, bd, a1);
                a2 = fmaf(-uv.z, bd, a2);
                a3 = fmaf(-uv.w, bd, a3);
            }
            const int k0 = h * 16 + g * 4;
            // 1-op key: exact order/value for positives; negatives land
            // < 0x80000000 (below every threshold -> never counted/summed).
            ua[k0 + 0] = __float_as_uint(a0) ^ 0x80000000u;
            ua[k0 + 1] = __float_as_uint(a1) ^ 0x80000000u;
            ua[k0 + 2] = __float_as_uint(a2) ^ 0x80000000u;
            ua[k0 + 3] = __float_as_uint(a3) ^ 0x80000000u;
        }
    }

    // Binary search for tau (64th largest), bits 30..8. Bit 31 pre-set (keys
    // of non-negative distances; >=64 of 2048 distances positive -- verified
    // eleven rounds). 24-bit truncation: final-mean bias < 1e-7 (threshold
    // 3.7e-4). cnt/threshold/decision are wave-uniform scalars.
    unsigned ca = 0x80000000u;
#pragma unroll 1
    for (int bit = 30; bit >= 8; --bit) {
        const unsigned ta = ca | (1u << bit);
        int cnt = 0;
#pragma unroll
        for (int j = 0; j < 32; ++j) cnt += __popcll(__ballot(ua[j] >= ta));
        if (cnt >= K_) ca = ta;
    }

    // Exact sum of strictly-greater values + tie adjustment at tau.
    float sa = 0.f;
    int ga = 0;
#pragma unroll
    for (int j = 0; j < 32; ++j) {
        const unsigned va = ua[j];
        const bool pa = va > ca;
        if (pa) sa += __uint_as_float(va ^ 0x80000000u);  // positives: exact inverse
        ga += __popcll(__ballot(pa));                     // wave-uniform
    }
#pragma unroll
    for (int o = 32; o; o >>= 1) sa += __shfl_xor(sa, o, 64);

    // Block reduction via sT corner (tile reads are complete; barrier first).
    __syncthreads();
    if (lane == 0) {
        const float tva = __uint_as_float(ca ^ 0x80000000u);
        const float qb = ws[WS_QB + b * N_ + n];
        sT[wave] = sa + (float)(K_ - ga) * tva + (float)K_ * qb;
    }
    __syncthreads();
    if (tid == 0) {
        float tsum = 0.f;
#pragma unroll
        for (int w = 0; w < 8; ++w) tsum += sT[w];
        ws[WS_PART + b * (N_ / 8) + blockIdx.x] = tsum;  // block-private, NO atomic
    }
}

// ---------------------------------------------------------------------------
// Kernel 3: sum the 2048 per-block partials, scale by exact 2^-20, write out.
// ---------------------------------------------------------------------------
__global__ __launch_bounds__(256) void finalize_kernel(const float* __restrict__ ws,
                                                       float* __restrict__ out)
{
    const int tid = threadIdx.x;
    float s = 0.f;
#pragma unroll
    for (int i = 0; i < 8; ++i) s += ws[WS_PART + i * 256 + tid];
#pragma unroll
    for (int o = 32; o; o >>= 1) s += __shfl_xor(s, o, 64);
    __shared__ float r4[4];
    if ((tid & 63) == 0) r4[tid >> 6] = s;
    __syncthreads();
    if (tid == 0) out[0] = (r4[0] + r4[1] + r4[2] + r4[3]) * (1.0f / 1048576.0f);
}

// ---------------------------------------------------------------------------
extern "C" void kernel_launch(void* const* d_in, const int* in_sizes, int n_in,
                              void* d_out, int out_size, void* d_ws, size_t ws_size,
                              hipStream_t stream)
{
    (void)in_sizes; (void)n_in; (void)out_size; (void)ws_size;
    const float* outputs = (const float*)d_in[0];  // (B,N,9) fp32
    const float* targets = (const float*)d_in[1];  // (B,M,9) fp32
    float* ws  = (float*)d_ws;
    float* out = (float*)d_out;

    stats_pinv_kernel<<<B_, 256, 0, stream>>>(outputs, targets, ws);
    topk_kernel<<<dim3(N_ / 8, B_), 512, 0, stream>>>(outputs, ws);
    finalize_kernel<<<1, 256, 0, stream>>>(ws, out);
}